// Round 4
// baseline (1910.804 us; speedup 1.0000x reference)
//
#include <hip/hip_runtime.h>
#include <math.h>

// MoDGMMFeatureModel, numpy-fp32-bit-exact (see round 3: angle channel requires
// exact replication of the np reference's rounding; frozen op orders:
//  - sgemm: acc=0, sequential-k __builtin_fmaf, bias added AFTER
//  - LN mean/var: numpy pairwise 8-accumulator pattern over the full vector
//  - elementwise: contract(off), left-assoc as written
//  - mod: fmodf + conditional += 2pi).
//
// Round-4 structure: 4 lanes per point (lane g owns j-slice of each layer's
// outputs) -> accumulator depth 128->32 -> ~4 waves/SIMD instead of 2.
// Activations staged in LDS [row][pt]; each point's column is touched only by
// its own wave's 4 lanes -> no __syncthreads anywhere.

constexpr int N_PTS = 1000000;
constexpr int GW = 64;
constexpr int FDIM = 32;
constexpr int DIN = 34;          // 2 + 32
constexpr int NH1 = 128;
constexpr int NH2 = 64;
constexpr int NOUT = 48;         // 6 * 8
constexpr int BLK = 256;
constexpr int PTS = 64;          // points per block = BLK/4

__global__ __launch_bounds__(BLK, 4) void modgmm_np32_split4(
    const float* __restrict__ coords,
    const float* __restrict__ grid,
    const float* __restrict__ W1, const float* __restrict__ b1,
    const float* __restrict__ g1, const float* __restrict__ be1,
    const float* __restrict__ W2, const float* __restrict__ b2,
    const float* __restrict__ g2, const float* __restrict__ be2,
    const float* __restrict__ W3, const float* __restrict__ b3,
    float* __restrict__ gmm_out, float* __restrict__ coords_out)
{
#pragma clang fp contract(off)
    __shared__ float buf[NH1 * PTS];          // 128 rows x 64 pts = 32 KB
    const int tid  = threadIdx.x;
    const int lane = tid & 63;
    const int g    = lane >> 4;               // 0..3: output-slice group
    const int pt   = ((tid >> 6) << 4) + (lane & 15);  // block-local point 0..63
    const int gi   = blockIdx.x * PTS + pt;   // global point (grid divides evenly)
#define BUF(r) buf[(r) * PTS + pt]

    // ---- coords + bilinear setup (all 4 lanes redundantly) ----
    const float2 c2 = reinterpret_cast<const float2*>(coords)[gi];
    const float cx = c2.x, cy = c2.y;
    const float x = cx * 63.0f;
    const float y = cy * 63.0f;
    int x0 = (int)floorf(x); x0 = x0 < 0 ? 0 : (x0 > 62 ? 62 : x0);
    int y0 = (int)floorf(y); y0 = y0 < 0 ? 0 : (y0 > 62 ? 62 : y0);
    const float dx = x - (float)x0;
    const float dy = y - (float)y0;
    const float omdx = 1.0f - dx;
    const float omdy = 1.0f - dy;
    const float w00 = omdx * omdy;
    const float w01 = omdx * dy;
    const float w10 = dx * omdy;
    const float w11 = dx * dy;

    if (g == 0) { BUF(0) = cx; BUF(1) = cy; }

    // lane g computes feat elems [g*8, g*8+8)
    {
        const float* gp = grid + (y0 * GW + x0) * FDIM + g * 8;
        const float4* q00 = reinterpret_cast<const float4*>(gp);
        const float4* q01 = reinterpret_cast<const float4*>(gp + GW * FDIM);
        const float4* q10 = reinterpret_cast<const float4*>(gp + FDIM);
        const float4* q11 = reinterpret_cast<const float4*>(gp + GW * FDIM + FDIM);
#pragma unroll
        for (int e = 0; e < 2; ++e) {
            const float4 a = q00[e], b = q01[e], c = q10[e], d = q11[e];
            const int r = 2 + g * 8 + e * 4;
            { const float t0 = w00*a.x, t1 = w01*b.x, t2 = w10*c.x, t3 = w11*d.x;
              BUF(r+0) = ((t0 + t1) + t2) + t3; }
            { const float t0 = w00*a.y, t1 = w01*b.y, t2 = w10*c.y, t3 = w11*d.y;
              BUF(r+1) = ((t0 + t1) + t2) + t3; }
            { const float t0 = w00*a.z, t1 = w01*b.z, t2 = w10*c.z, t3 = w11*d.z;
              BUF(r+2) = ((t0 + t1) + t2) + t3; }
            { const float t0 = w00*a.w, t1 = w01*b.w, t2 = w10*c.w, t3 = w11*d.w;
              BUF(r+3) = ((t0 + t1) + t2) + t3; }
        }
    }

    // ---- layer 1: 34 -> 128, lane owns j in [g*32, g*32+32) ----
    float acc[32];
#pragma unroll
    for (int jj = 0; jj < 32; ++jj) acc[jj] = 0.0f;
    for (int k = 0; k < DIN; ++k) {
        const float hv = BUF(k);
        const float4* w4 = reinterpret_cast<const float4*>(W1 + k * NH1 + g * 32);
#pragma unroll
        for (int q = 0; q < 8; ++q) {
            const float4 w = w4[q];
            acc[4*q+0] = __builtin_fmaf(hv, w.x, acc[4*q+0]);
            acc[4*q+1] = __builtin_fmaf(hv, w.y, acc[4*q+1]);
            acc[4*q+2] = __builtin_fmaf(hv, w.z, acc[4*q+2]);
            acc[4*q+3] = __builtin_fmaf(hv, w.w, acc[4*q+3]);
        }
    }
    // bias + relu, then publish to LDS rows g*32+jj
    {
        const float4* bv4 = reinterpret_cast<const float4*>(b1 + g * 32);
#pragma unroll
        for (int q = 0; q < 8; ++q) {
            const float4 bv = bv4[q];
            acc[4*q+0] = fmaxf(acc[4*q+0] + bv.x, 0.0f);
            acc[4*q+1] = fmaxf(acc[4*q+1] + bv.y, 0.0f);
            acc[4*q+2] = fmaxf(acc[4*q+2] + bv.z, 0.0f);
            acc[4*q+3] = fmaxf(acc[4*q+3] + bv.w, 0.0f);
        }
#pragma unroll
        for (int jj = 0; jj < 32; ++jj) BUF(g * 32 + jj) = acc[jj];
    }

    // ---- layernorm 1 (n=128): numpy pairwise from the full LDS column ----
    float mu1, rs1;
    {
        float r[8];
#pragma unroll
        for (int j = 0; j < 8; ++j) r[j] = BUF(j);
#pragma unroll
        for (int m = 1; m < 16; ++m)
#pragma unroll
            for (int j = 0; j < 8; ++j) r[j] = r[j] + BUF(8 * m + j);
        mu1 = (((r[0]+r[1]) + (r[2]+r[3])) + ((r[4]+r[5]) + (r[6]+r[7]))) / 128.0f;
#pragma unroll
        for (int j = 0; j < 8; ++j) { const float d = BUF(j) - mu1; r[j] = d * d; }
#pragma unroll
        for (int m = 1; m < 16; ++m)
#pragma unroll
            for (int j = 0; j < 8; ++j) {
                const float d = BUF(8 * m + j) - mu1;
                r[j] = r[j] + d * d;
            }
        const float var = (((r[0]+r[1]) + (r[2]+r[3])) + ((r[4]+r[5]) + (r[6]+r[7]))) / 128.0f;
        rs1 = 1.0f / sqrtf(var + 1e-5f);
    }
    // normalize own 32 (still in regs) and overwrite LDS
    {
        const float4* gv4 = reinterpret_cast<const float4*>(g1 + g * 32);
        const float4* ev4 = reinterpret_cast<const float4*>(be1 + g * 32);
#pragma unroll
        for (int q = 0; q < 8; ++q) {
            const float4 gv = gv4[q], ev = ev4[q];
            BUF(g*32 + 4*q+0) = ((acc[4*q+0] - mu1) * rs1) * gv.x + ev.x;
            BUF(g*32 + 4*q+1) = ((acc[4*q+1] - mu1) * rs1) * gv.y + ev.y;
            BUF(g*32 + 4*q+2) = ((acc[4*q+2] - mu1) * rs1) * gv.z + ev.z;
            BUF(g*32 + 4*q+3) = ((acc[4*q+3] - mu1) * rs1) * gv.w + ev.w;
        }
    }

    // ---- layer 2: 128 -> 64, lane owns j in [g*16, g*16+16) ----
    float acc2[16];
#pragma unroll
    for (int jj = 0; jj < 16; ++jj) acc2[jj] = 0.0f;
    for (int k = 0; k < NH1; ++k) {
        const float hv = BUF(k);
        const float4* w4 = reinterpret_cast<const float4*>(W2 + k * NH2 + g * 16);
#pragma unroll
        for (int q = 0; q < 4; ++q) {
            const float4 w = w4[q];
            acc2[4*q+0] = __builtin_fmaf(hv, w.x, acc2[4*q+0]);
            acc2[4*q+1] = __builtin_fmaf(hv, w.y, acc2[4*q+1]);
            acc2[4*q+2] = __builtin_fmaf(hv, w.z, acc2[4*q+2]);
            acc2[4*q+3] = __builtin_fmaf(hv, w.w, acc2[4*q+3]);
        }
    }
    {
        const float4* bv4 = reinterpret_cast<const float4*>(b2 + g * 16);
#pragma unroll
        for (int q = 0; q < 4; ++q) {
            const float4 bv = bv4[q];
            acc2[4*q+0] = fmaxf(acc2[4*q+0] + bv.x, 0.0f);
            acc2[4*q+1] = fmaxf(acc2[4*q+1] + bv.y, 0.0f);
            acc2[4*q+2] = fmaxf(acc2[4*q+2] + bv.z, 0.0f);
            acc2[4*q+3] = fmaxf(acc2[4*q+3] + bv.w, 0.0f);
        }
#pragma unroll
        for (int jj = 0; jj < 16; ++jj) BUF(g * 16 + jj) = acc2[jj];
    }

    // ---- layernorm 2 (n=64) ----
    float mu2, rs2;
    {
        float r[8];
#pragma unroll
        for (int j = 0; j < 8; ++j) r[j] = BUF(j);
#pragma unroll
        for (int m = 1; m < 8; ++m)
#pragma unroll
            for (int j = 0; j < 8; ++j) r[j] = r[j] + BUF(8 * m + j);
        mu2 = (((r[0]+r[1]) + (r[2]+r[3])) + ((r[4]+r[5]) + (r[6]+r[7]))) / 64.0f;
#pragma unroll
        for (int j = 0; j < 8; ++j) { const float d = BUF(j) - mu2; r[j] = d * d; }
#pragma unroll
        for (int m = 1; m < 8; ++m)
#pragma unroll
            for (int j = 0; j < 8; ++j) {
                const float d = BUF(8 * m + j) - mu2;
                r[j] = r[j] + d * d;
            }
        const float var = (((r[0]+r[1]) + (r[2]+r[3])) + ((r[4]+r[5]) + (r[6]+r[7]))) / 64.0f;
        rs2 = 1.0f / sqrtf(var + 1e-5f);
    }
    {
        const float4* gv4 = reinterpret_cast<const float4*>(g2 + g * 16);
        const float4* ev4 = reinterpret_cast<const float4*>(be2 + g * 16);
#pragma unroll
        for (int q = 0; q < 4; ++q) {
            const float4 gv = gv4[q], ev = ev4[q];
            BUF(g*16 + 4*q+0) = ((acc2[4*q+0] - mu2) * rs2) * gv.x + ev.x;
            BUF(g*16 + 4*q+1) = ((acc2[4*q+1] - mu2) * rs2) * gv.y + ev.y;
            BUF(g*16 + 4*q+2) = ((acc2[4*q+2] - mu2) * rs2) * gv.z + ev.z;
            BUF(g*16 + 4*q+3) = ((acc2[4*q+3] - mu2) * rs2) * gv.w + ev.w;
        }
    }

    // ---- layer 3: 64 -> 48, lane owns j in [g*12, g*12+12) ----
    float o[12];
#pragma unroll
    for (int jj = 0; jj < 12; ++jj) o[jj] = 0.0f;
    for (int k = 0; k < NH2; ++k) {
        const float hv = BUF(k);
        const float4* w4 = reinterpret_cast<const float4*>(W3 + k * NOUT + g * 12);
#pragma unroll
        for (int q = 0; q < 3; ++q) {
            const float4 w = w4[q];
            o[4*q+0] = __builtin_fmaf(hv, w.x, o[4*q+0]);
            o[4*q+1] = __builtin_fmaf(hv, w.y, o[4*q+1]);
            o[4*q+2] = __builtin_fmaf(hv, w.z, o[4*q+2]);
            o[4*q+3] = __builtin_fmaf(hv, w.w, o[4*q+3]);
        }
    }
    {
        const float4* bv4 = reinterpret_cast<const float4*>(b3 + g * 12);
#pragma unroll
        for (int q = 0; q < 3; ++q) {
            const float4 bv = bv4[q];
            o[4*q+0] = o[4*q+0] + bv.x;
            o[4*q+1] = o[4*q+1] + bv.y;
            o[4*q+2] = o[4*q+2] + bv.z;
            o[4*q+3] = o[4*q+3] + bv.w;
        }
    }

    // ---- GMM postprocess: lane owns components 2g (o[0..5]) and 2g+1 (o[6..11]) ----
    const float TPf = 6.28318530717958647692f;
    float res[12];
    // softmax over the 8 component logits o[6c+0]; max is order-independent
    float mp = fmaxf(o[0], o[6]);
    mp = fmaxf(mp, __shfl_xor(mp, 16));
    mp = fmaxf(mp, __shfl_xor(mp, 32));
    const float e0 = expf(o[0] - mp);
    const float e1 = expf(o[6] - mp);
    // numpy pairwise n=8 tree: ((e0+e1)+(e2+e3))+((e4+e5)+(e6+e7))
    const float s  = e0 + e1;                   // inner pair for comps {2g,2g+1}
    const float u  = s + __shfl_xor(s, 16);     // (g^1) pair -> quad sums (commutative)
    const float esum = u + __shfl_xor(u, 32);   // final tree sum, identical all lanes
    res[0] = e0 / esum;
    res[6] = e1 / esum;
#pragma unroll
    for (int h = 0; h < 2; ++h) {
        const int off = 6 * h;
        res[off+1] = fmaxf(o[off+1], 0.0f);
        float a = fmodf(o[off+2], TPf);
        if (a < 0.0f) a += TPf;
        res[off+2] = a;
        res[off+3] = expf(fminf(fmaxf(o[off+3], -10.0f), 10.0f));
        res[off+4] = expf(fminf(fmaxf(o[off+4], -10.0f), 10.0f));
        res[off+5] = 0.99f * tanhf(o[off+5]);
    }

    // ---- stores ----
    float4* og = reinterpret_cast<float4*>(gmm_out + (size_t)gi * NOUT + g * 12);
    og[0] = make_float4(res[0], res[1], res[2],  res[3]);
    og[1] = make_float4(res[4], res[5], res[6],  res[7]);
    og[2] = make_float4(res[8], res[9], res[10], res[11]);
    if (g == 0)
        reinterpret_cast<float2*>(coords_out)[gi] = make_float2(cx, cy);
#undef BUF
}

extern "C" void kernel_launch(void* const* d_in, const int* in_sizes, int n_in,
                              void* d_out, int out_size, void* d_ws, size_t ws_size,
                              hipStream_t stream) {
    const float* coords = (const float*)d_in[0];
    const float* grid   = (const float*)d_in[1];
    const float* W1  = (const float*)d_in[2];
    const float* b1  = (const float*)d_in[3];
    const float* g1  = (const float*)d_in[4];
    const float* be1 = (const float*)d_in[5];
    const float* W2  = (const float*)d_in[6];
    const float* b2  = (const float*)d_in[7];
    const float* g2  = (const float*)d_in[8];
    const float* be2 = (const float*)d_in[9];
    const float* W3  = (const float*)d_in[10];
    const float* b3  = (const float*)d_in[11];

    float* gmm_out    = (float*)d_out;                          // N*48 floats
    float* coords_out = (float*)d_out + (size_t)N_PTS * NOUT;   // N*2 floats

    const int nblocks = N_PTS / PTS;   // 1e6 / 64 = 15625, exact
    modgmm_np32_split4<<<nblocks, BLK, 0, stream>>>(
        coords, grid, W1, b1, g1, be1, W2, b2, g2, be2, W3, b3,
        gmm_out, coords_out);
}

// Round 5
// 1440.209 us; speedup vs baseline: 1.3268x; 1.3268x over previous
//
#include <hip/hip_runtime.h>
#include <math.h>

// MoDGMMFeatureModel, numpy-fp32-bit-exact (frozen op orders, proven round 3):
//  - sgemm: acc=0, sequential-k __builtin_fmaf, bias added AFTER (own rounding)
//  - LN mean/var: numpy pairwise 8-accumulator pattern
//  - elementwise: contract(off), left-assoc as written
//  - mod: fmodf + conditional += 2pi
// Round 5: round-3 structure (1 thread = 1 point, coalesced 192B stores,
// wave-uniform weights) + weights staged per-layer in a 32KB LDS region so the
// k-loop reads weights via in-order ds_read_b128 broadcasts instead of SMEM
// batch drains. 5 barriers; no early return (threads clamp, stores guarded).

constexpr int N_PTS = 1000000;
constexpr int GW = 64;
constexpr int FDIM = 32;
constexpr int DIN = 34;          // 2 + 32
constexpr int NH1 = 128;
constexpr int NH2 = 64;
constexpr int NOUT = 48;         // 6 * 8
constexpr int NC = 8;
constexpr int BLK = 128;

// numpy pairwise_sum for N in {64,128} (8-accumulator pattern)
template<int N>
__device__ __forceinline__ float np_pairwise(const float* x) {
#pragma clang fp contract(off)
    float r[8];
#pragma unroll
    for (int j = 0; j < 8; ++j) r[j] = x[j];
#pragma unroll
    for (int m = 1; m < N / 8; ++m)
#pragma unroll
        for (int j = 0; j < 8; ++j) r[j] = r[j] + x[8 * m + j];
    return ((r[0] + r[1]) + (r[2] + r[3])) + ((r[4] + r[5]) + (r[6] + r[7]));
}

template<int N>
__device__ __forceinline__ float np_pairwise_sq(const float* x, float mu) {
#pragma clang fp contract(off)
    float r[8];
#pragma unroll
    for (int j = 0; j < 8; ++j) { const float d = x[j] - mu; r[j] = d * d; }
#pragma unroll
    for (int m = 1; m < N / 8; ++m)
#pragma unroll
        for (int j = 0; j < 8; ++j) {
            const float d = x[8 * m + j] - mu;
            r[j] = r[j] + d * d;
        }
    return ((r[0] + r[1]) + (r[2] + r[3])) + ((r[4] + r[5]) + (r[6] + r[7]));
}

__global__ __launch_bounds__(BLK, 2) void modgmm_np32_ldsw(
    const float* __restrict__ coords,
    const float* __restrict__ grid,
    const float* __restrict__ W1, const float* __restrict__ b1,
    const float* __restrict__ g1, const float* __restrict__ be1,
    const float* __restrict__ W2, const float* __restrict__ b2,
    const float* __restrict__ g2, const float* __restrict__ be2,
    const float* __restrict__ W3, const float* __restrict__ b3,
    float* __restrict__ gmm_out, float* __restrict__ coords_out)
{
#pragma clang fp contract(off)
    __shared__ float sbuf[64 * BLK];   // 32 KB activation staging [row][tid]
    __shared__ float wlds[8192];       // 32 KB weight region (W1/W2/W3 reuse)
    const int tid = threadIdx.x;
    const int i_raw = blockIdx.x * BLK + tid;
    const int i = i_raw < N_PTS ? i_raw : N_PTS - 1;   // clamp; stores guarded

    // ---- stage W1 (4352 floats = 1088 float4) ----
    {
        const float4* src = reinterpret_cast<const float4*>(W1);
        float4* dst = reinterpret_cast<float4*>(wlds);
        for (int idx = tid; idx < 1088; idx += BLK) dst[idx] = src[idx];
    }

    const float2 c2 = reinterpret_cast<const float2*>(coords)[i];
    const float cx = c2.x, cy = c2.y;

    // ---- bilinear gather, numpy op order (identical to round 3) ----
    const float x = cx * 63.0f;
    const float y = cy * 63.0f;
    int x0 = (int)floorf(x); x0 = x0 < 0 ? 0 : (x0 > 62 ? 62 : x0);
    int y0 = (int)floorf(y); y0 = y0 < 0 ? 0 : (y0 > 62 ? 62 : y0);
    const float dx = x - (float)x0;
    const float dy = y - (float)y0;
    const float omdx = 1.0f - dx;
    const float omdy = 1.0f - dy;
    const float w00 = omdx * omdy;
    const float w01 = omdx * dy;
    const float w10 = dx * omdy;
    const float w11 = dx * dy;

    const float* __restrict__ gp = grid + (y0 * GW + x0) * FDIM;

    sbuf[0 * BLK + tid] = cx;
    sbuf[1 * BLK + tid] = cy;
#pragma unroll
    for (int k = 0; k < FDIM; ++k) {
        const float t0 = w00 * gp[k];
        const float t1 = w01 * gp[GW * FDIM + k];
        const float t2 = w10 * gp[FDIM + k];
        const float t3 = w11 * gp[GW * FDIM + FDIM + k];
        sbuf[(2 + k) * BLK + tid] = ((t0 + t1) + t2) + t3;
    }

    __syncthreads();   // W1 staged

    // ---- layer 1: 34 -> 128 (acc=0, sequential-k FMA, weights from LDS) ----
    float h[NH1];
#pragma unroll
    for (int j = 0; j < NH1; ++j) h[j] = 0.0f;
    for (int k = 0; k < DIN; ++k) {
        const float hv = sbuf[k * BLK + tid];
        const float* wr = wlds + k * NH1;
#pragma unroll
        for (int q = 0; q < NH1 / 4; ++q) {
            const float4 w = *reinterpret_cast<const float4*>(wr + 4 * q);
            h[4*q+0] = __builtin_fmaf(hv, w.x, h[4*q+0]);
            h[4*q+1] = __builtin_fmaf(hv, w.y, h[4*q+1]);
            h[4*q+2] = __builtin_fmaf(hv, w.z, h[4*q+2]);
            h[4*q+3] = __builtin_fmaf(hv, w.w, h[4*q+3]);
        }
    }
#pragma unroll
    for (int j = 0; j < NH1; ++j) h[j] = fmaxf(h[j] + b1[j], 0.0f);

    // ---- layernorm 1 ----
    {
        const float mu = np_pairwise<NH1>(h) / 128.0f;
        const float var = np_pairwise_sq<NH1>(h, mu) / 128.0f;
        const float rs = 1.0f / sqrtf(var + 1e-5f);
#pragma unroll
        for (int j = 0; j < NH1; ++j)
            h[j] = ((h[j] - mu) * rs) * g1[j] + be1[j];
    }

    __syncthreads();   // all waves done reading W1
    // ---- stage W2 (8192 floats = 2048 float4) ----
    {
        const float4* src = reinterpret_cast<const float4*>(W2);
        float4* dst = reinterpret_cast<float4*>(wlds);
        for (int idx = tid; idx < 2048; idx += BLK) dst[idx] = src[idx];
    }
    __syncthreads();   // W2 staged

    // ---- layer 2: 128 -> 64, act staged in two 64-row halves ----
    float h2[NH2];
#pragma unroll
    for (int j = 0; j < NH2; ++j) h2[j] = 0.0f;
#pragma unroll
    for (int j = 0; j < 64; ++j) sbuf[j * BLK + tid] = h[j];
    for (int k = 0; k < 64; ++k) {
        const float hv = sbuf[k * BLK + tid];
        const float* wr = wlds + k * NH2;
#pragma unroll
        for (int q = 0; q < NH2 / 4; ++q) {
            const float4 w = *reinterpret_cast<const float4*>(wr + 4 * q);
            h2[4*q+0] = __builtin_fmaf(hv, w.x, h2[4*q+0]);
            h2[4*q+1] = __builtin_fmaf(hv, w.y, h2[4*q+1]);
            h2[4*q+2] = __builtin_fmaf(hv, w.z, h2[4*q+2]);
            h2[4*q+3] = __builtin_fmaf(hv, w.w, h2[4*q+3]);
        }
    }
#pragma unroll
    for (int j = 0; j < 64; ++j) sbuf[j * BLK + tid] = h[64 + j];
    for (int k = 0; k < 64; ++k) {
        const float hv = sbuf[k * BLK + tid];
        const float* wr = wlds + (64 + k) * NH2;
#pragma unroll
        for (int q = 0; q < NH2 / 4; ++q) {
            const float4 w = *reinterpret_cast<const float4*>(wr + 4 * q);
            h2[4*q+0] = __builtin_fmaf(hv, w.x, h2[4*q+0]);
            h2[4*q+1] = __builtin_fmaf(hv, w.y, h2[4*q+1]);
            h2[4*q+2] = __builtin_fmaf(hv, w.z, h2[4*q+2]);
            h2[4*q+3] = __builtin_fmaf(hv, w.w, h2[4*q+3]);
        }
    }
#pragma unroll
    for (int j = 0; j < NH2; ++j) h2[j] = fmaxf(h2[j] + b2[j], 0.0f);

    // ---- layernorm 2 ----
    {
        const float mu = np_pairwise<NH2>(h2) / 64.0f;
        const float var = np_pairwise_sq<NH2>(h2, mu) / 64.0f;
        const float rs = 1.0f / sqrtf(var + 1e-5f);
#pragma unroll
        for (int j = 0; j < NH2; ++j)
            h2[j] = ((h2[j] - mu) * rs) * g2[j] + be2[j];
    }

    __syncthreads();   // all waves done reading W2
    // ---- stage W3 (3072 floats = 768 float4) ----
    {
        const float4* src = reinterpret_cast<const float4*>(W3);
        float4* dst = reinterpret_cast<float4*>(wlds);
        for (int idx = tid; idx < 768; idx += BLK) dst[idx] = src[idx];
    }
    __syncthreads();   // W3 staged

    // ---- layer 3: 64 -> 48 ----
    float o[NOUT];
#pragma unroll
    for (int j = 0; j < NOUT; ++j) o[j] = 0.0f;
#pragma unroll
    for (int j = 0; j < NH2; ++j) sbuf[j * BLK + tid] = h2[j];
    for (int k = 0; k < NH2; ++k) {
        const float hv = sbuf[k * BLK + tid];
        const float* wr = wlds + k * NOUT;
#pragma unroll
        for (int q = 0; q < NOUT / 4; ++q) {
            const float4 w = *reinterpret_cast<const float4*>(wr + 4 * q);
            o[4*q+0] = __builtin_fmaf(hv, w.x, o[4*q+0]);
            o[4*q+1] = __builtin_fmaf(hv, w.y, o[4*q+1]);
            o[4*q+2] = __builtin_fmaf(hv, w.z, o[4*q+2]);
            o[4*q+3] = __builtin_fmaf(hv, w.w, o[4*q+3]);
        }
    }
#pragma unroll
    for (int j = 0; j < NOUT; ++j) o[j] = o[j] + b3[j];

    // ---- GMM postprocess (identical to round 3) ----
    const float TPf = 6.28318530717958647692f;
    float res[NOUT];
    float m = o[0];
#pragma unroll
    for (int c = 1; c < NC; ++c) m = fmaxf(m, o[6 * c]);
    float e[NC];
#pragma unroll
    for (int c = 0; c < NC; ++c) e[c] = expf(o[6 * c] - m);
    const float esum = ((e[0] + e[1]) + (e[2] + e[3])) + ((e[4] + e[5]) + (e[6] + e[7]));
#pragma unroll
    for (int c = 0; c < NC; ++c) {
        res[6 * c + 0] = e[c] / esum;
        res[6 * c + 1] = fmaxf(o[6 * c + 1], 0.0f);
        float a = fmodf(o[6 * c + 2], TPf);
        if (a < 0.0f) a += TPf;
        res[6 * c + 2] = a;
        res[6 * c + 3] = expf(fminf(fmaxf(o[6 * c + 3], -10.0f), 10.0f));
        res[6 * c + 4] = expf(fminf(fmaxf(o[6 * c + 4], -10.0f), 10.0f));
        res[6 * c + 5] = 0.99f * tanhf(o[6 * c + 5]);
    }

    // ---- stores (coalesced, 192 B contiguous per thread) ----
    if (i_raw < N_PTS) {
        float4* og = reinterpret_cast<float4*>(gmm_out + (size_t)i_raw * NOUT);
#pragma unroll
        for (int q = 0; q < NOUT / 4; ++q)
            og[q] = make_float4(res[4 * q + 0], res[4 * q + 1], res[4 * q + 2], res[4 * q + 3]);
        reinterpret_cast<float2*>(coords_out)[i_raw] = make_float2(cx, cy);
    }
}

extern "C" void kernel_launch(void* const* d_in, const int* in_sizes, int n_in,
                              void* d_out, int out_size, void* d_ws, size_t ws_size,
                              hipStream_t stream) {
    const float* coords = (const float*)d_in[0];
    const float* grid   = (const float*)d_in[1];
    const float* W1  = (const float*)d_in[2];
    const float* b1  = (const float*)d_in[3];
    const float* g1  = (const float*)d_in[4];
    const float* be1 = (const float*)d_in[5];
    const float* W2  = (const float*)d_in[6];
    const float* b2  = (const float*)d_in[7];
    const float* g2  = (const float*)d_in[8];
    const float* be2 = (const float*)d_in[9];
    const float* W3  = (const float*)d_in[10];
    const float* b3  = (const float*)d_in[11];

    float* gmm_out    = (float*)d_out;                          // N*48 floats
    float* coords_out = (float*)d_out + (size_t)N_PTS * NOUT;   // N*2 floats

    const int nblocks = (N_PTS + BLK - 1) / BLK;
    modgmm_np32_ldsw<<<nblocks, BLK, 0, stream>>>(
        coords, grid, W1, b1, g1, be1, W2, b2, g2, be2, W3, b3,
        gmm_out, coords_out);
}